// Round 3
// baseline (777.023 us; speedup 1.0000x reference)
//
#include <hip/hip_runtime.h>
#include <stdint.h>

typedef short bf16x8 __attribute__((ext_vector_type(8)));
typedef float f32x4 __attribute__((ext_vector_type(4)));
typedef unsigned short u16x4 __attribute__((ext_vector_type(4)));

__device__ __forceinline__ unsigned short f2b(float f) {
  union { float f; unsigned u; } v; v.f = f;
  unsigned r = v.u + 0x7fffu + ((v.u >> 16) & 1u);
  return (unsigned short)(r >> 16);
}
__device__ __forceinline__ float fsigm(float x) { return 1.f / (1.f + __expf(-x)); }
__device__ __forceinline__ float ftanh(float x) {
  float t = __expf(-2.f * fabsf(x));
  float r = (1.f - t) / (1.f + t);
  return copysignf(r, x);
}

// ---------------- fused transpose+convert: f32[R][C] -> bf16 out[C][R], 12 matrices ----------------
struct TD { const float* in; unsigned short* out; int R, C; };
struct TDs { TD d[12]; };

__global__ __launch_bounds__(256) void tconv_all(TDs ds) {
  TD t = ds.d[blockIdx.z];
  int c0 = blockIdx.x * 32, r0 = blockIdx.y * 32;
  if (c0 >= t.C || r0 >= t.R) return;
  __shared__ float tl[32][33];
  int tx = threadIdx.x & 31, ty = threadIdx.x >> 5;  // 32 x 8
  #pragma unroll
  for (int i = 0; i < 32; i += 8) {
    int r = r0 + ty + i, c = c0 + tx;
    tl[ty + i][tx] = (r < t.R && c < t.C) ? t.in[(size_t)r * t.C + c] : 0.f;
  }
  __syncthreads();
  #pragma unroll
  for (int i = 0; i < 32; i += 8) {
    int c = c0 + ty + i, r = r0 + tx;
    if (c < t.C && r < t.R) t.out[(size_t)c * t.R + r] = f2b(tl[tx][ty + i]);
  }
}

// ---------------- f32 -> bf16 flat convert ----------------
__global__ __launch_bounds__(256) void conv_k(const float* __restrict__ in,
                                              unsigned short* __restrict__ out, int n) {
  int i = (blockIdx.x * 256 + threadIdx.x) * 8;
  if (i >= n) return;
  float4 a = *(const float4*)(in + i);
  float4 b = *(const float4*)(in + i + 4);
  bf16x8 v;
  v[0] = (short)f2b(a.x); v[1] = (short)f2b(a.y); v[2] = (short)f2b(a.z); v[3] = (short)f2b(a.w);
  v[4] = (short)f2b(b.x); v[5] = (short)f2b(b.y); v[6] = (short)f2b(b.z); v[7] = (short)f2b(b.w);
  *(bf16x8*)(out + i) = v;
}

// ---------------- generic MFMA GEMM: C = act(A[M,K] @ BT[N,K]^T + bias) ----------------
template <int ACT, bool OBF16, bool NT>
__global__ __launch_bounds__(256) void gemm_k(const unsigned short* __restrict__ A,
                                              const unsigned short* __restrict__ BT,
                                              const float* __restrict__ bias,
                                              void* __restrict__ Cp,
                                              int M, int N, int K, int ldC) {
  __shared__ unsigned short As[64][40];
  __shared__ unsigned short Bs[64][40];
  const int tid = threadIdx.x;
  const int n0 = blockIdx.x * 64;
  const int m0 = blockIdx.y * 64;
  const int wid = tid >> 6, lane = tid & 63;
  const int wm = (wid >> 1) * 32, wn = (wid & 1) * 32;
  const int lr = lane & 15, lk = lane >> 4;
  const int sr = tid >> 2, sc = (tid & 3) * 8;

  f32x4 acc[2][2] = {};

  for (int k0 = 0; k0 < K; k0 += 32) {
    *(bf16x8*)&As[sr][sc] = *(const bf16x8*)(A + (size_t)(m0 + sr) * K + k0 + sc);
    {
      int n = n0 + sr;
      bf16x8 v = {};
      if (n < N) v = *(const bf16x8*)(BT + (size_t)n * K + k0 + sc);
      *(bf16x8*)&Bs[sr][sc] = v;
    }
    __syncthreads();
    bf16x8 af[2], bfr[2];
    #pragma unroll
    for (int mi = 0; mi < 2; mi++) af[mi] = *(const bf16x8*)&As[wm + mi * 16 + lr][lk * 8];
    #pragma unroll
    for (int ni = 0; ni < 2; ni++) bfr[ni] = *(const bf16x8*)&Bs[wn + ni * 16 + lr][lk * 8];
    #pragma unroll
    for (int mi = 0; mi < 2; mi++)
      #pragma unroll
      for (int ni = 0; ni < 2; ni++)
        acc[mi][ni] = __builtin_amdgcn_mfma_f32_16x16x32_bf16(af[mi], bfr[ni], acc[mi][ni], 0, 0, 0);
    __syncthreads();
  }

  #pragma unroll
  for (int mi = 0; mi < 2; mi++)
    #pragma unroll
    for (int ni = 0; ni < 2; ni++) {
      int col = n0 + wn + ni * 16 + lr;
      if (col >= N) continue;
      float bv = bias[col];
      #pragma unroll
      for (int r = 0; r < 4; r++) {
        int row = m0 + wm + mi * 16 + lk * 4 + r;
        float v = acc[mi][ni][r] + bv;
        if (ACT == 1) v = fmaxf(v, 0.f);
        if (OBF16) ((unsigned short*)Cp)[(size_t)row * ldC + col] = f2b(v);
        else if (NT) __builtin_nontemporal_store(v, (float*)Cp + (size_t)row * ldC + col);
        else       ((float*)Cp)[(size_t)row * ldC + col] = v;
      }
    }
}

// ---------------- fused LSTM scan over 16 steps (1024 threads, 16 waves) ----------------
__global__ __launch_bounds__(1024) void lstm_k(const float* __restrict__ c0,
                                               const unsigned short* __restrict__ whhT,  // [512][128]
                                               const float* __restrict__ w_ih,           // [16][512]
                                               const float* __restrict__ b_ih,
                                               const float* __restrict__ b_hh,
                                               unsigned short* __restrict__ h_all) {     // [8192][16][128]
  __shared__ float G[32][516];
  __shared__ float cst[32][128];
  __shared__ unsigned short hst[32][136];
  const int tid = threadIdx.x, lane = tid & 63, wid = tid >> 6;  // wid 0..15
  const int r0 = blockIdx.x * 32;
  const int lr = lane & 15, lk = lane >> 4;

  {
    int r = tid >> 5, j4 = (tid & 31) * 4;
    float4 c4 = *(const float4*)(c0 + (size_t)(r0 + r) * 128 + j4);
    *(f32x4*)&cst[r][j4] = f32x4{c4.x, c4.y, c4.z, c4.w};
    u16x4 h4;
    h4[0] = f2b(ftanh(c4.x)); h4[1] = f2b(ftanh(c4.y));
    h4[2] = f2b(ftanh(c4.z)); h4[3] = f2b(ftanh(c4.w));
    *(u16x4*)&hst[r][j4] = h4;
  }
  __syncthreads();

  for (int a = 0; a < 16; a++) {
    f32x4 acc[2][2] = {};
    #pragma unroll
    for (int ks = 0; ks < 4; ks++) {
      bf16x8 af0 = *(const bf16x8*)&hst[lr][ks * 32 + lk * 8];
      bf16x8 af1 = *(const bf16x8*)&hst[16 + lr][ks * 32 + lk * 8];
      #pragma unroll
      for (int nj = 0; nj < 2; nj++) {
        int col = wid * 32 + nj * 16 + lr;
        bf16x8 bv = *(const bf16x8*)(whhT + (size_t)col * 128 + ks * 32 + lk * 8);
        acc[0][nj] = __builtin_amdgcn_mfma_f32_16x16x32_bf16(af0, bv, acc[0][nj], 0, 0, 0);
        acc[1][nj] = __builtin_amdgcn_mfma_f32_16x16x32_bf16(af1, bv, acc[1][nj], 0, 0, 0);
      }
    }
    #pragma unroll
    for (int mi = 0; mi < 2; mi++)
      #pragma unroll
      for (int nj = 0; nj < 2; nj++)
        #pragma unroll
        for (int rr = 0; rr < 4; rr++)
          G[mi * 16 + lk * 4 + rr][wid * 32 + nj * 16 + lr] = acc[mi][nj][rr];
    __syncthreads();

    const float* ig = w_ih + a * 512;
    #pragma unroll
    for (int it = 0; it < 4; it++) {
      int e = tid + it * 1024;
      int r = e >> 7, j = e & 127;
      float gi = G[r][j]       + ig[j]       + b_ih[j]       + b_hh[j];
      float gf = G[r][j + 128] + ig[j + 128] + b_ih[j + 128] + b_hh[j + 128];
      float gg = G[r][j + 256] + ig[j + 256] + b_ih[j + 256] + b_hh[j + 256];
      float go = G[r][j + 384] + ig[j + 384] + b_ih[j + 384] + b_hh[j + 384];
      float c = cst[r][j];
      float cn = fsigm(gf) * c + fsigm(gi) * ftanh(gg);
      float h = fsigm(go) * ftanh(cn);
      cst[r][j] = cn;
      unsigned short hb = f2b(h);
      hst[r][j] = hb;
      h_all[((size_t)(r0 + r) * 16 + a) * 128 + j] = hb;
    }
    __syncthreads();
  }
}

// ---------------- fused head MLPs v2 ----------------
// w1cat: [384][128] (z|q|a hidden), w2cat: [1217][128] (z 600 | q 601 | a 16)
__global__ __launch_bounds__(256) void heads_k(
    const unsigned short* __restrict__ hall,  // [131072][128]
    const unsigned short* __restrict__ w1cat,
    const float* __restrict__ zb1, const float* __restrict__ qb1, const float* __restrict__ ab1,
    const unsigned short* __restrict__ w2cat,
    const float* __restrict__ zb2, const float* __restrict__ qb2, const float* __restrict__ ab2,
    float* __restrict__ oz, float* __restrict__ oq, float* __restrict__ oa) {
  __shared__ unsigned short hs[64][136];
  __shared__ unsigned short hd[64][392];   // 384 + 8 pad (row stride ≡ 4 banks)
  const int tid = threadIdx.x;
  const int r0 = blockIdx.x * 64;
  const int lane = tid & 63, wid = tid >> 6;
  const int lr = lane & 15, lk = lane >> 4;

  {
    int row = tid >> 2, cb = (tid & 3) * 8;
    #pragma unroll
    for (int it = 0; it < 4; it++) {
      int col = cb + it * 32;
      *(bf16x8*)&hs[row][col] = *(const bf16x8*)(hall + (size_t)(r0 + row) * 128 + col);
    }
  }
  __syncthreads();

  // ---- hidden: 24 frags (384 cols), wave wid owns frags [wid*6, wid*6+6) ----
  {
    bf16x8 ha[4][4];
    #pragma unroll
    for (int mi = 0; mi < 4; mi++)
      #pragma unroll
      for (int ks = 0; ks < 4; ks++)
        ha[mi][ks] = *(const bf16x8*)&hs[mi * 16 + lr][ks * 32 + lk * 8];
    #pragma unroll
    for (int j = 0; j < 6; j++) {
      int nf = wid * 6 + j;
      int col = nf * 16 + lr;
      bf16x8 bv[4];
      #pragma unroll
      for (int ks = 0; ks < 4; ks++)
        bv[ks] = *(const bf16x8*)(w1cat + (size_t)col * 128 + ks * 32 + lk * 8);
      f32x4 hacc[4] = {};
      #pragma unroll
      for (int ks = 0; ks < 4; ks++)
        #pragma unroll
        for (int mi = 0; mi < 4; mi++)
          hacc[mi] = __builtin_amdgcn_mfma_f32_16x16x32_bf16(ha[mi][ks], bv[ks], hacc[mi], 0, 0, 0);
      float bb = (col < 128) ? zb1[col] : (col < 256) ? qb1[col - 128] : ab1[col - 256];
      #pragma unroll
      for (int mi = 0; mi < 4; mi++)
        #pragma unroll
        for (int rr = 0; rr < 4; rr++)
          hd[mi * 16 + lk * 4 + rr][col] = f2b(fmaxf(hacc[mi][rr] + bb, 0.f));
    }
  }
  __syncthreads();

  // ---- outputs: per head, static frag counts; frags round-robin over waves ----
  #pragma unroll
  for (int hi = 0; hi < 3; hi++) {
    const int NF = (hi == 0) ? 38 : (hi == 1) ? 38 : 1;
    const int Nh = (hi == 0) ? 600 : (hi == 1) ? 601 : 16;
    const int so = (hi == 0) ? 0 : (hi == 1) ? 600 : 1201;
    const float* b2 = (hi == 0) ? zb2 : (hi == 1) ? qb2 : ab2;
    float* Oh = (hi == 0) ? oz : (hi == 1) ? oq : oa;

    bf16x8 hda[4][4];
    #pragma unroll
    for (int mi = 0; mi < 4; mi++)
      #pragma unroll
      for (int ks = 0; ks < 4; ks++)
        hda[mi][ks] = *(const bf16x8*)&hd[mi * 16 + lr][hi * 128 + ks * 32 + lk * 8];

    for (int f = wid; f < NF; f += 4) {
      int col = f * 16 + lr;
      int bc = col < Nh ? col : Nh - 1;
      bf16x8 bv[4];
      #pragma unroll
      for (int ks = 0; ks < 4; ks++)
        bv[ks] = *(const bf16x8*)(w2cat + (size_t)(so + bc) * 128 + ks * 32 + lk * 8);
      f32x4 oacc[4] = {};
      #pragma unroll
      for (int ks = 0; ks < 4; ks++)
        #pragma unroll
        for (int mi = 0; mi < 4; mi++)
          oacc[mi] = __builtin_amdgcn_mfma_f32_16x16x32_bf16(hda[mi][ks], bv[ks], oacc[mi], 0, 0, 0);
      if (col < Nh) {
        float bb = b2[col];
        #pragma unroll
        for (int mi = 0; mi < 4; mi++)
          #pragma unroll
          for (int rr = 0; rr < 4; rr++)
            __builtin_nontemporal_store(oacc[mi][rr] + bb,
                Oh + (size_t)(r0 + mi * 16 + lk * 4 + rr) * Nh + col);
      }
    }
  }
}

extern "C" void kernel_launch(void* const* d_in, const int* in_sizes, int n_in,
                              void* d_out, int out_size, void* d_ws, size_t ws_size,
                              hipStream_t stream) {
  const float* obs   = (const float*)d_in[0];
  const float* bb_w1 = (const float*)d_in[1];
  const float* bb_b1 = (const float*)d_in[2];
  const float* bb_w2 = (const float*)d_in[3];
  const float* bb_b2 = (const float*)d_in[4];
  const float* pol_w = (const float*)d_in[5];
  const float* pol_b = (const float*)d_in[6];
  const float* y_w   = (const float*)d_in[7];
  const float* y_b   = (const float*)d_in[8];
  const float* ci_w  = (const float*)d_in[9];
  const float* ci_b  = (const float*)d_in[10];
  const float* w_ih  = (const float*)d_in[11];
  const float* w_hh  = (const float*)d_in[12];
  const float* b_ih  = (const float*)d_in[13];
  const float* b_hh  = (const float*)d_in[14];
  const float* z_w1  = (const float*)d_in[15];
  const float* z_b1  = (const float*)d_in[16];
  const float* z_w2  = (const float*)d_in[17];
  const float* z_b2  = (const float*)d_in[18];
  const float* q_w1  = (const float*)d_in[19];
  const float* q_b1  = (const float*)d_in[20];
  const float* q_w2  = (const float*)d_in[21];
  const float* q_b2  = (const float*)d_in[22];
  const float* a_w1  = (const float*)d_in[23];
  const float* a_b1  = (const float*)d_in[24];
  const float* a_w2  = (const float*)d_in[25];
  const float* a_b2  = (const float*)d_in[26];

  float* out = (float*)d_out;
  float* out_logits = out;                 // [8192][16]
  float* out_y      = out + 131072;        // [8192][600]
  float* out_z      = out + 5046272;       // [131072][600]
  float* out_q      = out + 83689472;      // [131072][601]
  float* out_a      = out + 162463744;     // [131072][16]

  uint8_t* ws = (uint8_t*)d_ws;
  size_t off = 0;
  auto alc = [&](size_t bytes) -> void* {
    void* p = ws + off;
    off = (off + bytes + 255) & ~(size_t)255;
    return p;
  };
  unsigned short* W1T  = (unsigned short*)alc((size_t)512 * 1024 * 2);
  unsigned short* W2T  = (unsigned short*)alc((size_t)512 * 512 * 2);
  unsigned short* polT = (unsigned short*)alc((size_t)16 * 512 * 2);
  unsigned short* yT   = (unsigned short*)alc((size_t)600 * 512 * 2);
  unsigned short* ciT  = (unsigned short*)alc((size_t)128 * 512 * 2);
  unsigned short* whhT = (unsigned short*)alc((size_t)512 * 128 * 2);
  // w1cat: z|q|a hidden weights contiguous (each 32768 B, 256-aligned)
  unsigned short* zw1T = (unsigned short*)alc((size_t)128 * 128 * 2);
  unsigned short* qw1T = (unsigned short*)alc((size_t)128 * 128 * 2);
  unsigned short* aw1T = (unsigned short*)alc((size_t)128 * 128 * 2);
  // w2cat: z|q|a output weights contiguous (153600 / 153856 / 4096 B, all 256-aligned)
  unsigned short* zw2T = (unsigned short*)alc((size_t)600 * 128 * 2);
  unsigned short* qw2T = (unsigned short*)alc((size_t)601 * 128 * 2);
  unsigned short* aw2T = (unsigned short*)alc((size_t)16 * 128 * 2);
  unsigned short* obsb = (unsigned short*)alc((size_t)8192 * 1024 * 2);
  unsigned short* hid1 = (unsigned short*)alc((size_t)8192 * 512 * 2);
  unsigned short* emb  = (unsigned short*)alc((size_t)8192 * 512 * 2);
  float*          c0b  = (float*)alc((size_t)8192 * 128 * 4);
  unsigned short* hall = (unsigned short*)alc((size_t)8192 * 16 * 128 * 2);
  (void)ws_size; (void)in_sizes; (void)n_in; (void)out_size;

  dim3 B256(256);

  TDs td;
  td.d[0]  = {bb_w1, W1T, 1024, 512};
  td.d[1]  = {bb_w2, W2T, 512, 512};
  td.d[2]  = {pol_w, polT, 512, 16};
  td.d[3]  = {y_w,   yT,   512, 600};
  td.d[4]  = {ci_w,  ciT,  512, 128};
  td.d[5]  = {w_hh,  whhT, 128, 512};
  td.d[6]  = {z_w1,  zw1T, 128, 128};
  td.d[7]  = {z_w2,  zw2T, 128, 600};
  td.d[8]  = {q_w1,  qw1T, 128, 128};
  td.d[9]  = {q_w2,  qw2T, 128, 601};
  td.d[10] = {a_w1,  aw1T, 128, 128};
  td.d[11] = {a_w2,  aw2T, 128, 16};
  tconv_all<<<dim3(19, 32, 12), B256, 0, stream>>>(td);

  conv_k<<<dim3(4096), B256, 0, stream>>>(obs, obsb, 8192 * 1024);

  // backbone
  gemm_k<1, true,  false><<<dim3(8, 128), B256, 0, stream>>>(obsb, W1T, bb_b1, hid1, 8192, 512, 1024, 512);
  gemm_k<1, true,  false><<<dim3(8, 128), B256, 0, stream>>>(hid1, W2T, bb_b2, emb,  8192, 512, 512,  512);
  // heads from emb
  gemm_k<0, false, true><<<dim3(1, 128),  B256, 0, stream>>>(emb, polT, pol_b, out_logits, 8192, 16,  512, 16);
  gemm_k<0, false, true><<<dim3(10, 128), B256, 0, stream>>>(emb, yT,   y_b,   out_y,      8192, 600, 512, 600);
  gemm_k<0, false, false><<<dim3(2, 128), B256, 0, stream>>>(emb, ciT,  ci_b,  c0b,        8192, 128, 512, 128);
  // fused LSTM scan (16 waves/block)
  lstm_k<<<dim3(256), dim3(1024), 0, stream>>>(c0b, whhT, w_ih, b_ih, b_hh, hall);
  // fused head MLPs
  heads_k<<<dim3(2048), B256, 0, stream>>>(hall,
                                           zw1T, z_b1, q_b1, a_b1,
                                           zw2T, z_b2, q_b2, a_b2,
                                           out_z, out_q, out_a);
}

// Round 4
// 481.731 us; speedup vs baseline: 1.6130x; 1.6130x over previous
//
#include <hip/hip_runtime.h>
#include <stdint.h>

typedef short bf16x8 __attribute__((ext_vector_type(8)));
typedef float f32x4 __attribute__((ext_vector_type(4)));
typedef unsigned short u16x4 __attribute__((ext_vector_type(4)));

__device__ __forceinline__ unsigned short f2b(float f) {
  union { float f; unsigned u; } v; v.f = f;
  unsigned r = v.u + 0x7fffu + ((v.u >> 16) & 1u);
  return (unsigned short)(r >> 16);
}
__device__ __forceinline__ float fsigm(float x) { return 1.f / (1.f + __expf(-x)); }
__device__ __forceinline__ float ftanh(float x) {
  float t = __expf(-2.f * fabsf(x));
  float r = (1.f - t) / (1.f + t);
  return copysignf(r, x);
}

// ---------------- fused transpose+convert: f32[R][C] -> bf16 out[C][R], 12 matrices ----------------
struct TD { const float* in; unsigned short* out; int R, C; };
struct TDs { TD d[12]; };

__global__ __launch_bounds__(256) void tconv_all(TDs ds) {
  TD t = ds.d[blockIdx.z];
  int c0 = blockIdx.x * 32, r0 = blockIdx.y * 32;
  if (c0 >= t.C || r0 >= t.R) return;
  __shared__ float tl[32][33];
  int tx = threadIdx.x & 31, ty = threadIdx.x >> 5;  // 32 x 8
  #pragma unroll
  for (int i = 0; i < 32; i += 8) {
    int r = r0 + ty + i, c = c0 + tx;
    tl[ty + i][tx] = (r < t.R && c < t.C) ? t.in[(size_t)r * t.C + c] : 0.f;
  }
  __syncthreads();
  #pragma unroll
  for (int i = 0; i < 32; i += 8) {
    int c = c0 + ty + i, r = r0 + tx;
    if (c < t.C && r < t.R) t.out[(size_t)c * t.R + r] = f2b(tl[tx][ty + i]);
  }
}

// ---------------- f32 -> bf16 flat convert ----------------
__global__ __launch_bounds__(256) void conv_k(const float* __restrict__ in,
                                              unsigned short* __restrict__ out, int n) {
  int i = (blockIdx.x * 256 + threadIdx.x) * 8;
  if (i >= n) return;
  float4 a = *(const float4*)(in + i);
  float4 b = *(const float4*)(in + i + 4);
  bf16x8 v;
  v[0] = (short)f2b(a.x); v[1] = (short)f2b(a.y); v[2] = (short)f2b(a.z); v[3] = (short)f2b(a.w);
  v[4] = (short)f2b(b.x); v[5] = (short)f2b(b.y); v[6] = (short)f2b(b.z); v[7] = (short)f2b(b.w);
  *(bf16x8*)(out + i) = v;
}

// ---------------- generic MFMA GEMM: C = act(A[M,K] @ BT[N,K]^T + bias) ----------------
template <int ACT, bool OBF16>
__global__ __launch_bounds__(256) void gemm_k(const unsigned short* __restrict__ A,
                                              const unsigned short* __restrict__ BT,
                                              const float* __restrict__ bias,
                                              void* __restrict__ Cp,
                                              int M, int N, int K, int ldC) {
  __shared__ unsigned short As[64][40];
  __shared__ unsigned short Bs[64][40];
  const int tid = threadIdx.x;
  const int n0 = blockIdx.x * 64;
  const int m0 = blockIdx.y * 64;
  const int wid = tid >> 6, lane = tid & 63;
  const int wm = (wid >> 1) * 32, wn = (wid & 1) * 32;
  const int lr = lane & 15, lk = lane >> 4;
  const int sr = tid >> 2, sc = (tid & 3) * 8;

  f32x4 acc[2][2] = {};

  for (int k0 = 0; k0 < K; k0 += 32) {
    *(bf16x8*)&As[sr][sc] = *(const bf16x8*)(A + (size_t)(m0 + sr) * K + k0 + sc);
    {
      int n = n0 + sr;
      bf16x8 v = {};
      if (n < N) v = *(const bf16x8*)(BT + (size_t)n * K + k0 + sc);
      *(bf16x8*)&Bs[sr][sc] = v;
    }
    __syncthreads();
    bf16x8 af[2], bfr[2];
    #pragma unroll
    for (int mi = 0; mi < 2; mi++) af[mi] = *(const bf16x8*)&As[wm + mi * 16 + lr][lk * 8];
    #pragma unroll
    for (int ni = 0; ni < 2; ni++) bfr[ni] = *(const bf16x8*)&Bs[wn + ni * 16 + lr][lk * 8];
    #pragma unroll
    for (int mi = 0; mi < 2; mi++)
      #pragma unroll
      for (int ni = 0; ni < 2; ni++)
        acc[mi][ni] = __builtin_amdgcn_mfma_f32_16x16x32_bf16(af[mi], bfr[ni], acc[mi][ni], 0, 0, 0);
    __syncthreads();
  }

  #pragma unroll
  for (int mi = 0; mi < 2; mi++)
    #pragma unroll
    for (int ni = 0; ni < 2; ni++) {
      int col = n0 + wn + ni * 16 + lr;
      if (col >= N) continue;
      float bv = bias[col];
      #pragma unroll
      for (int r = 0; r < 4; r++) {
        int row = m0 + wm + mi * 16 + lk * 4 + r;
        float v = acc[mi][ni][r] + bv;
        if (ACT == 1) v = fmaxf(v, 0.f);
        if (OBF16) ((unsigned short*)Cp)[(size_t)row * ldC + col] = f2b(v);
        else       ((float*)Cp)[(size_t)row * ldC + col] = v;
      }
    }
}

// ---------------- fused LSTM scan over 16 steps (1024 threads, 16 waves) ----------------
__global__ __launch_bounds__(1024) void lstm_k(const float* __restrict__ c0,
                                               const unsigned short* __restrict__ whhT,  // [512][128]
                                               const float* __restrict__ w_ih,           // [16][512]
                                               const float* __restrict__ b_ih,
                                               const float* __restrict__ b_hh,
                                               unsigned short* __restrict__ h_all) {     // [8192][16][128]
  __shared__ float G[32][516];
  __shared__ float cst[32][128];
  __shared__ unsigned short hst[32][136];
  const int tid = threadIdx.x, lane = tid & 63, wid = tid >> 6;  // wid 0..15
  const int r0 = blockIdx.x * 32;
  const int lr = lane & 15, lk = lane >> 4;

  {
    int r = tid >> 5, j4 = (tid & 31) * 4;
    float4 c4 = *(const float4*)(c0 + (size_t)(r0 + r) * 128 + j4);
    *(f32x4*)&cst[r][j4] = f32x4{c4.x, c4.y, c4.z, c4.w};
    u16x4 h4;
    h4[0] = f2b(ftanh(c4.x)); h4[1] = f2b(ftanh(c4.y));
    h4[2] = f2b(ftanh(c4.z)); h4[3] = f2b(ftanh(c4.w));
    *(u16x4*)&hst[r][j4] = h4;
  }
  __syncthreads();

  for (int a = 0; a < 16; a++) {
    f32x4 acc[2][2] = {};
    #pragma unroll
    for (int ks = 0; ks < 4; ks++) {
      bf16x8 af0 = *(const bf16x8*)&hst[lr][ks * 32 + lk * 8];
      bf16x8 af1 = *(const bf16x8*)&hst[16 + lr][ks * 32 + lk * 8];
      #pragma unroll
      for (int nj = 0; nj < 2; nj++) {
        int col = wid * 32 + nj * 16 + lr;
        bf16x8 bv = *(const bf16x8*)(whhT + (size_t)col * 128 + ks * 32 + lk * 8);
        acc[0][nj] = __builtin_amdgcn_mfma_f32_16x16x32_bf16(af0, bv, acc[0][nj], 0, 0, 0);
        acc[1][nj] = __builtin_amdgcn_mfma_f32_16x16x32_bf16(af1, bv, acc[1][nj], 0, 0, 0);
      }
    }
    #pragma unroll
    for (int mi = 0; mi < 2; mi++)
      #pragma unroll
      for (int nj = 0; nj < 2; nj++)
        #pragma unroll
        for (int rr = 0; rr < 4; rr++)
          G[mi * 16 + lk * 4 + rr][wid * 32 + nj * 16 + lr] = acc[mi][nj][rr];
    __syncthreads();

    const float* ig = w_ih + a * 512;
    #pragma unroll
    for (int it = 0; it < 4; it++) {
      int e = tid + it * 1024;
      int r = e >> 7, j = e & 127;
      float gi = G[r][j]       + ig[j]       + b_ih[j]       + b_hh[j];
      float gf = G[r][j + 128] + ig[j + 128] + b_ih[j + 128] + b_hh[j + 128];
      float gg = G[r][j + 256] + ig[j + 256] + b_ih[j + 256] + b_hh[j + 256];
      float go = G[r][j + 384] + ig[j + 384] + b_ih[j + 384] + b_hh[j + 384];
      float c = cst[r][j];
      float cn = fsigm(gf) * c + fsigm(gi) * ftanh(gg);
      float h = fsigm(go) * ftanh(cn);
      cst[r][j] = cn;
      unsigned short hb = f2b(h);
      hst[r][j] = hb;
      h_all[((size_t)(r0 + r) * 16 + a) * 128 + j] = hb;
    }
    __syncthreads();
  }
}

// ---------------- fused head MLPs v3: small LDS (4 blk/CU) + w2 prefetch ----------------
// w1cat: [384][128] (z|q|a hidden), w2cat: [1217][128] (z 600 | q 601 | a 16)
__global__ __launch_bounds__(256, 4) void heads_k(
    const unsigned short* __restrict__ hall,  // [131072][128]
    const unsigned short* __restrict__ w1cat,
    const unsigned short* __restrict__ w2cat,
    const float* __restrict__ zb1, const float* __restrict__ qb1, const float* __restrict__ ab1,
    const float* __restrict__ zb2, const float* __restrict__ qb2, const float* __restrict__ ab2,
    float* __restrict__ oz, float* __restrict__ oq, float* __restrict__ oa) {
  __shared__ unsigned short hs[64][136];  // hall tile   (272B stride ≡ 16 mod 128: conflict-free b128)
  __shared__ unsigned short hd[64][136];  // hidden tile (reused per head)
  const int tid = threadIdx.x;
  const int r0 = blockIdx.x * 64;
  const int lane = tid & 63, wid = tid >> 6;
  const int lr = lane & 15, lk = lane >> 4;

  {
    int row = tid >> 2, cb = (tid & 3) * 8;
    #pragma unroll
    for (int it = 0; it < 4; it++) {
      int col = cb + it * 32;
      *(bf16x8*)&hs[row][col] = *(const bf16x8*)(hall + (size_t)(r0 + row) * 128 + col);
    }
  }
  __syncthreads();

  const float* B1a[3] = {zb1, qb1, ab1};
  const float* B2a[3] = {zb2, qb2, ab2};
  float*       OOa[3] = {oz, oq, oa};

  #pragma unroll
  for (int hi = 0; hi < 3; hi++) {
    const int NF = (hi == 0) ? 38 : (hi == 1) ? 38 : 1;
    const int Nh = (hi == 0) ? 600 : (hi == 1) ? 601 : 16;
    const int so = (hi == 0) ? 0 : (hi == 1) ? 600 : 1201;
    const float* b1 = B1a[hi];
    const float* b2 = B2a[hi];
    float* Oh = OOa[hi];

    // ---- hidden: 8 frags (128 cols), wave wid owns frags {wid*2, wid*2+1} ----
    {
      bf16x8 w1v[2][4];
      #pragma unroll
      for (int j = 0; j < 2; j++) {
        int col = (wid * 2 + j) * 16 + lr;
        #pragma unroll
        for (int ks = 0; ks < 4; ks++)
          w1v[j][ks] = *(const bf16x8*)(w1cat + (size_t)(hi * 128 + col) * 128 + ks * 32 + lk * 8);
      }
      f32x4 hacc[2][4] = {};
      #pragma unroll
      for (int ks = 0; ks < 4; ks++) {
        bf16x8 av[4];
        #pragma unroll
        for (int mi = 0; mi < 4; mi++)
          av[mi] = *(const bf16x8*)&hs[mi * 16 + lr][ks * 32 + lk * 8];
        #pragma unroll
        for (int j = 0; j < 2; j++)
          #pragma unroll
          for (int mi = 0; mi < 4; mi++)
            hacc[j][mi] = __builtin_amdgcn_mfma_f32_16x16x32_bf16(av[mi], w1v[j][ks], hacc[j][mi], 0, 0, 0);
      }
      #pragma unroll
      for (int j = 0; j < 2; j++) {
        int col = (wid * 2 + j) * 16 + lr;
        float bb = b1[col];
        #pragma unroll
        for (int mi = 0; mi < 4; mi++)
          #pragma unroll
          for (int rr = 0; rr < 4; rr++)
            hd[mi * 16 + lk * 4 + rr][col] = f2b(fmaxf(hacc[j][mi][rr] + bb, 0.f));
      }
    }
    __syncthreads();

    // ---- output: frags round-robin over waves, 1-deep register prefetch of w2 ----
    {
      bf16x8 hda[4][4];
      #pragma unroll
      for (int mi = 0; mi < 4; mi++)
        #pragma unroll
        for (int ks = 0; ks < 4; ks++)
          hda[mi][ks] = *(const bf16x8*)&hd[mi * 16 + lr][ks * 32 + lk * 8];

      bf16x8 bvA[4], bvB[4];
      int f = wid;
      if (f < NF) {
        int bc = min(f * 16 + lr, Nh - 1);
        #pragma unroll
        for (int ks = 0; ks < 4; ks++)
          bvA[ks] = *(const bf16x8*)(w2cat + (size_t)(so + bc) * 128 + ks * 32 + lk * 8);
      }
      for (; f < NF; f += 4) {
        int fn = f + 4;
        if (fn < NF) {
          int bc = min(fn * 16 + lr, Nh - 1);
          #pragma unroll
          for (int ks = 0; ks < 4; ks++)
            bvB[ks] = *(const bf16x8*)(w2cat + (size_t)(so + bc) * 128 + ks * 32 + lk * 8);
        }
        f32x4 oacc[4] = {};
        #pragma unroll
        for (int ks = 0; ks < 4; ks++)
          #pragma unroll
          for (int mi = 0; mi < 4; mi++)
            oacc[mi] = __builtin_amdgcn_mfma_f32_16x16x32_bf16(hda[mi][ks], bvA[ks], oacc[mi], 0, 0, 0);
        int col = f * 16 + lr;
        if (col < Nh) {
          float bb = b2[col];
          #pragma unroll
          for (int mi = 0; mi < 4; mi++)
            #pragma unroll
            for (int rr = 0; rr < 4; rr++)
              Oh[(size_t)(r0 + mi * 16 + lk * 4 + rr) * Nh + col] = oacc[mi][rr] + bb;
        }
        #pragma unroll
        for (int ks = 0; ks < 4; ks++) bvA[ks] = bvB[ks];
      }
    }
    __syncthreads();
  }
}

extern "C" void kernel_launch(void* const* d_in, const int* in_sizes, int n_in,
                              void* d_out, int out_size, void* d_ws, size_t ws_size,
                              hipStream_t stream) {
  const float* obs   = (const float*)d_in[0];
  const float* bb_w1 = (const float*)d_in[1];
  const float* bb_b1 = (const float*)d_in[2];
  const float* bb_w2 = (const float*)d_in[3];
  const float* bb_b2 = (const float*)d_in[4];
  const float* pol_w = (const float*)d_in[5];
  const float* pol_b = (const float*)d_in[6];
  const float* y_w   = (const float*)d_in[7];
  const float* y_b   = (const float*)d_in[8];
  const float* ci_w  = (const float*)d_in[9];
  const float* ci_b  = (const float*)d_in[10];
  const float* w_ih  = (const float*)d_in[11];
  const float* w_hh  = (const float*)d_in[12];
  const float* b_ih  = (const float*)d_in[13];
  const float* b_hh  = (const float*)d_in[14];
  const float* z_w1  = (const float*)d_in[15];
  const float* z_b1  = (const float*)d_in[16];
  const float* z_w2  = (const float*)d_in[17];
  const float* z_b2  = (const float*)d_in[18];
  const float* q_w1  = (const float*)d_in[19];
  const float* q_b1  = (const float*)d_in[20];
  const float* q_w2  = (const float*)d_in[21];
  const float* q_b2  = (const float*)d_in[22];
  const float* a_w1  = (const float*)d_in[23];
  const float* a_b1  = (const float*)d_in[24];
  const float* a_w2  = (const float*)d_in[25];
  const float* a_b2  = (const float*)d_in[26];

  float* out = (float*)d_out;
  float* out_logits = out;                 // [8192][16]
  float* out_y      = out + 131072;        // [8192][600]
  float* out_z      = out + 5046272;       // [131072][600]
  float* out_q      = out + 83689472;      // [131072][601]
  float* out_a      = out + 162463744;     // [131072][16]

  uint8_t* ws = (uint8_t*)d_ws;
  size_t off = 0;
  auto alc = [&](size_t bytes) -> void* {
    void* p = ws + off;
    off = (off + bytes + 255) & ~(size_t)255;
    return p;
  };
  unsigned short* W1T  = (unsigned short*)alc((size_t)512 * 1024 * 2);
  unsigned short* W2T  = (unsigned short*)alc((size_t)512 * 512 * 2);
  unsigned short* polT = (unsigned short*)alc((size_t)16 * 512 * 2);
  unsigned short* yT   = (unsigned short*)alc((size_t)600 * 512 * 2);
  unsigned short* ciT  = (unsigned short*)alc((size_t)128 * 512 * 2);
  unsigned short* whhT = (unsigned short*)alc((size_t)512 * 128 * 2);
  // w1cat: z|q|a hidden weights contiguous (each 32768 B, 256-aligned)
  unsigned short* zw1T = (unsigned short*)alc((size_t)128 * 128 * 2);
  unsigned short* qw1T = (unsigned short*)alc((size_t)128 * 128 * 2);
  unsigned short* aw1T = (unsigned short*)alc((size_t)128 * 128 * 2);
  // w2cat: z|q|a output weights contiguous (153600 / 153856 / 4096 B, all 256-aligned)
  unsigned short* zw2T = (unsigned short*)alc((size_t)600 * 128 * 2);
  unsigned short* qw2T = (unsigned short*)alc((size_t)601 * 128 * 2);
  unsigned short* aw2T = (unsigned short*)alc((size_t)16 * 128 * 2);
  unsigned short* obsb = (unsigned short*)alc((size_t)8192 * 1024 * 2);
  unsigned short* hid1 = (unsigned short*)alc((size_t)8192 * 512 * 2);
  unsigned short* emb  = (unsigned short*)alc((size_t)8192 * 512 * 2);
  float*          c0b  = (float*)alc((size_t)8192 * 128 * 4);
  unsigned short* hall = (unsigned short*)alc((size_t)8192 * 16 * 128 * 2);
  (void)ws_size; (void)in_sizes; (void)n_in; (void)out_size;

  dim3 B256(256);

  TDs td;
  td.d[0]  = {bb_w1, W1T, 1024, 512};
  td.d[1]  = {bb_w2, W2T, 512, 512};
  td.d[2]  = {pol_w, polT, 512, 16};
  td.d[3]  = {y_w,   yT,   512, 600};
  td.d[4]  = {ci_w,  ciT,  512, 128};
  td.d[5]  = {w_hh,  whhT, 128, 512};
  td.d[6]  = {z_w1,  zw1T, 128, 128};
  td.d[7]  = {z_w2,  zw2T, 128, 600};
  td.d[8]  = {q_w1,  qw1T, 128, 128};
  td.d[9]  = {q_w2,  qw2T, 128, 601};
  td.d[10] = {a_w1,  aw1T, 128, 128};
  td.d[11] = {a_w2,  aw2T, 128, 16};
  tconv_all<<<dim3(19, 32, 12), B256, 0, stream>>>(td);

  conv_k<<<dim3(4096), B256, 0, stream>>>(obs, obsb, 8192 * 1024);

  // backbone
  gemm_k<1, true><<<dim3(8, 128), B256, 0, stream>>>(obsb, W1T, bb_b1, hid1, 8192, 512, 1024, 512);
  gemm_k<1, true><<<dim3(8, 128), B256, 0, stream>>>(hid1, W2T, bb_b2, emb,  8192, 512, 512,  512);
  // heads from emb
  gemm_k<0, false><<<dim3(1, 128),  B256, 0, stream>>>(emb, polT, pol_b, out_logits, 8192, 16,  512, 16);
  gemm_k<0, false><<<dim3(10, 128), B256, 0, stream>>>(emb, yT,   y_b,   out_y,      8192, 600, 512, 600);
  gemm_k<0, false><<<dim3(2, 128),  B256, 0, stream>>>(emb, ciT,  ci_b,  c0b,        8192, 128, 512, 128);
  // fused LSTM scan (16 waves/block)
  lstm_k<<<dim3(256), dim3(1024), 0, stream>>>(c0b, whhT, w_ih, b_ih, b_hh, hall);
  // fused head MLPs
  heads_k<<<dim3(2048), B256, 0, stream>>>(hall,
                                           zw1T, zw2T,
                                           z_b1, q_b1, a_b1,
                                           z_b2, q_b2, a_b2,
                                           out_z, out_q, out_a);
}